// Round 1
// baseline (107.847 us; speedup 1.0000x reference)
//
#include <hip/hip_runtime.h>

// Problem shape is fixed by the reference: (B,H,W,D) = (4,128,128,128), fp32.
// Layout row-major, D innermost. Total floats = 8,388,608 = 2,097,152 float4s.
//
// R = -2*exp(-2*Phi) * (lap + 2*|grad Phi|^2),  Phi = pos - lam*neg,
// stencil neighbors edge-clamped (pad mode='edge'), h = 1.

#define NVEC (4 * 128 * 128 * 32)   // total float4 elements

__global__ __launch_bounds__(256) void conformal_kernel(
    const float* __restrict__ pos, const float* __restrict__ neg,
    const float* __restrict__ lamp, float* __restrict__ out)
{
    const float lam = lamp[0];
    const int vid = blockIdx.x * blockDim.x + threadIdx.x;  // float4 index
    if (vid >= NVEC) return;

    const int dvec = vid & 31;          // which float4 along D (32 per row)
    const int w    = (vid >> 5)  & 127;
    const int h    = (vid >> 12) & 127;
    // b = vid >> 19 (never crosses a clamp boundary; not needed)

    const float4* posv = (const float4*)pos;
    const float4* negv = (const float4*)neg;

    // Edge clamp: out-of-range neighbor index folds back to center.
    const int i_yp = (w < 127) ? vid + 32   : vid;
    const int i_ym = (w > 0)   ? vid - 32   : vid;
    const int i_xp = (h < 127) ? vid + 4096 : vid;
    const int i_xm = (h > 0)   ? vid - 4096 : vid;

    float4 p_c  = posv[vid],  n_c  = negv[vid];
    float4 p_yp = posv[i_yp], n_yp = negv[i_yp];
    float4 p_ym = posv[i_ym], n_ym = negv[i_ym];
    float4 p_xp = posv[i_xp], n_xp = negv[i_xp];
    float4 p_xm = posv[i_xm], n_xm = negv[i_xm];

    const int fbase = vid << 2;   // flat float index of lane's element 0
    // z-direction edge scalars (one element left / right of the vector)
    float pl = 0.f, nl = 0.f, pr = 0.f, nr = 0.f;
    if (dvec > 0)  { pl = pos[fbase - 1]; nl = neg[fbase - 1]; }
    if (dvec < 31) { pr = pos[fbase + 4]; nr = neg[fbase + 4]; }

    // Phi = pos - lam*neg
    float c[4];
    c[0] = p_c.x - lam * n_c.x;
    c[1] = p_c.y - lam * n_c.y;
    c[2] = p_c.z - lam * n_c.z;
    c[3] = p_c.w - lam * n_c.w;

    const float left  = (dvec > 0)  ? (pl - lam * nl) : c[0];  // Phi[d=-1] clamps to Phi[0]
    const float right = (dvec < 31) ? (pr - lam * nr) : c[3];  // Phi[d=128] clamps to Phi[127]

    float xpv[4], xmv[4], ypv[4], ymv[4];
    xpv[0] = p_xp.x - lam * n_xp.x;  xpv[1] = p_xp.y - lam * n_xp.y;
    xpv[2] = p_xp.z - lam * n_xp.z;  xpv[3] = p_xp.w - lam * n_xp.w;
    xmv[0] = p_xm.x - lam * n_xm.x;  xmv[1] = p_xm.y - lam * n_xm.y;
    xmv[2] = p_xm.z - lam * n_xm.z;  xmv[3] = p_xm.w - lam * n_xm.w;
    ypv[0] = p_yp.x - lam * n_yp.x;  ypv[1] = p_yp.y - lam * n_yp.y;
    ypv[2] = p_yp.z - lam * n_yp.z;  ypv[3] = p_yp.w - lam * n_yp.w;
    ymv[0] = p_ym.x - lam * n_ym.x;  ymv[1] = p_ym.y - lam * n_ym.y;
    ymv[2] = p_ym.z - lam * n_ym.z;  ymv[3] = p_ym.w - lam * n_ym.w;

    const float zl[4] = { left, c[0], c[1], c[2] };   // Phi at d-1
    const float zr[4] = { c[1], c[2], c[3], right };  // Phi at d+1

    float r[4];
#pragma unroll
    for (int j = 0; j < 4; ++j) {
        const float gx = (xpv[j] - xmv[j]) * 0.5f;
        const float gy = (ypv[j] - ymv[j]) * 0.5f;
        const float gz = (zr[j]  - zl[j])  * 0.5f;
        const float grad_sq = gx * gx + gy * gy + gz * gz;
        const float lap = xpv[j] + xmv[j] + ypv[j] + ymv[j] + zl[j] + zr[j]
                          - 6.0f * c[j];
        r[j] = -2.0f * __expf(-2.0f * c[j]) * (lap + 2.0f * grad_sq);
    }

    float4 o;
    o.x = r[0]; o.y = r[1]; o.z = r[2]; o.w = r[3];
    ((float4*)out)[vid] = o;
}

extern "C" void kernel_launch(void* const* d_in, const int* in_sizes, int n_in,
                              void* d_out, int out_size, void* d_ws, size_t ws_size,
                              hipStream_t stream) {
    const float* pos = (const float*)d_in[0];
    const float* neg = (const float*)d_in[1];
    const float* lam = (const float*)d_in[2];
    float* out = (float*)d_out;

    const int threads = 256;
    const int blocks  = NVEC / threads;  // 8192
    conformal_kernel<<<blocks, threads, 0, stream>>>(pos, neg, lam, out);
}